// Round 6
// baseline (64.200 us; speedup 1.0000x reference)
//
#include <hip/hip_runtime.h>
#include <hip/hip_bf16.h>
#include <math.h>

#define B_  128
#define N_  16
#define T_  200
#define H_  64
#define J1  80
#define J2  40
#define NTILE 13
#define ZSTR  208              // per-bn score stride (13*16)
#define NEGV -4294967295.0f   // -2^32 + 1

typedef __attribute__((ext_vector_type(8))) short bf16x8;
typedef __attribute__((ext_vector_type(4))) float f32x4;

__device__ __forceinline__ float sigmoidf_(float x) {
    return 1.0f / (1.0f + __expf(-x));
}
// branch-free RNE f32->bf16 (finite inputs only)
__device__ __forceinline__ short f2b(float x) {
    unsigned u = __float_as_uint(x);
    return (short)((u + 0x7FFF + ((u >> 16) & 1)) >> 16);
}
__device__ __forceinline__ unsigned pack2(float a, float b) {
    return (unsigned)(unsigned short)f2b(a) | ((unsigned)(unsigned short)f2b(b) << 16);
}

// ---- fused prep: ONE dispatch, 4 independent block ranges ---------------
// [0,160):        QW[bn][j]  = b1[j] + sum_h q*(W1a+W1c)        (2048*20 thr)
// [160,5280):     Bnf frag-ordered bf16: q[h]*W1d[h][j]+W1b-W1c (2048*640 thr)
// [5280,5696):    keys -> frag-ordered bf16 A-frags             (128*13*64 thr)
// [5696,5705):    W2 -> frag-ordered bf16 (k pad 96, m pad 48)  (2304 thr)
#define QW_BLK   160
#define BNF_BLK  5120
#define KBF_BLK  416
#define W2F_BLK  9
__global__ void prep_all(const float* __restrict__ queries,
                         const float* __restrict__ keys,
                         const float* __restrict__ W1,
                         const float* __restrict__ b1,
                         const float* __restrict__ W2,
                         float* __restrict__ QW,
                         bf16x8* __restrict__ Bnf,
                         bf16x8* __restrict__ kbf0, bf16x8* __restrict__ kbf1,
                         unsigned* __restrict__ W2F) {
    const int blk = blockIdx.x, tid = threadIdx.x;
    if (blk < QW_BLK) {
        int idx = blk * 256 + tid;                 // (bn, j/4), exact fit
        int bn = idx / 20, j = (idx % 20) * 4;
        float4 acc = *(const float4*)(b1 + j);
        const float* qp = queries + bn * H_;
        for (int h = 0; h < H_; ++h) {
            float qh = qp[h];
            float4 wa = *(const float4*)(W1 + h * J1 + j);
            float4 wc = *(const float4*)(W1 + (128 + h) * J1 + j);
            acc.x = fmaf(qh, wa.x + wc.x, acc.x);
            acc.y = fmaf(qh, wa.y + wc.y, acc.y);
            acc.z = fmaf(qh, wa.z + wc.z, acc.z);
            acc.w = fmaf(qh, wa.w + wc.w, acc.w);
        }
        *(float4*)(QW + bn * J1 + j) = acc;
    } else if (blk < QW_BLK + BNF_BLK) {
        // thread per (bn, f, l): 8 shorts, h=(f&1)*32+(l>>4)*8+r, j=(f>>1)*16+(l&15)
        int idx = (blk - QW_BLK) * 256 + tid;      // exact fit
        int l = idx & 63, f = (idx >> 6) % 10, bn = idx / 640;
        int j  = (f >> 1) * 16 + (l & 15);
        int h0 = (f & 1) * 32 + (l >> 4) * 8;
        const float* qp = queries + bn * H_ + h0;
        float v[8];
        #pragma unroll
        for (int r = 0; r < 8; ++r) {
            int h = h0 + r;
            float wd = W1[(192 + h) * J1 + j];
            float wb = W1[( 64 + h) * J1 + j];
            float wc = W1[(128 + h) * J1 + j];
            v[r] = fmaf(qp[r], wd, wb - wc);
        }
        uint4 o = make_uint4(pack2(v[0], v[1]), pack2(v[2], v[3]),
                             pack2(v[4], v[5]), pack2(v[6], v[7]));
        *(uint4*)(Bnf + idx) = o;                  // coalesced 16B
    } else if (blk < QW_BLK + BNF_BLK + KBF_BLK) {
        int idx = (blk - QW_BLK - BNF_BLK) * 256 + tid;   // (b*13+mt)*64+l, exact
        int l  = idx & 63, bm = idx >> 6;
        int mt = bm % NTILE, b = bm / NTILE;
        int t  = mt * 16 + (l & 15); if (t > T_ - 1) t = T_ - 1;
        int rg = l >> 4;
        const float* kr = keys + ((size_t)(b * T_ + t)) * H_ + 8 * rg;
        float4 a0 = *(const float4*)(kr);
        float4 a1 = *(const float4*)(kr + 4);
        float4 a2 = *(const float4*)(kr + 32);
        float4 a3 = *(const float4*)(kr + 36);
        bf16x8 f0, f1;
        f0[0] = f2b(a0.x); f0[1] = f2b(a0.y); f0[2] = f2b(a0.z); f0[3] = f2b(a0.w);
        f0[4] = f2b(a1.x); f0[5] = f2b(a1.y); f0[6] = f2b(a1.z); f0[7] = f2b(a1.w);
        f1[0] = f2b(a2.x); f1[1] = f2b(a2.y); f1[2] = f2b(a2.z); f1[3] = f2b(a2.w);
        f1[4] = f2b(a3.x); f1[5] = f2b(a3.y); f1[6] = f2b(a3.z); f1[7] = f2b(a3.w);
        kbf0[idx] = f0; kbf1[idx] = f1;
    } else {
        int idx = (blk - QW_BLK - BNF_BLK - KBF_BLK) * 256 + tid;
        if (idx < 9 * 64 * 4) {
            int rp = idx & 3;
            int l  = (idx >> 2) & 63;
            int f  = idx >> 8;
            int m  = (f / 3) * 16 + (l & 15);
            int k0 = (f % 3) * 32 + 8 * (l >> 4) + 2 * rp;
            float a = (k0     < J1 && m < J2) ? W2[k0 * J2 + m]       : 0.0f;
            float b = (k0 + 1 < J1 && m < J2) ? W2[(k0 + 1) * J2 + m] : 0.0f;
            W2F[idx] = pack2(a, b);
        }
    }
}

// ---- scores: ONE WAVE per (bn, mt) job; no barriers, pure dataflow ------
// 26624 jobs = 6656 blocks x 4 waves. All operands single-use coalesced loads.
__global__ __launch_bounds__(256, 4) void score_mfma(
        const float* __restrict__ QW,
        const bf16x8* __restrict__ Bnf,
        const bf16x8* __restrict__ kbf0, const bf16x8* __restrict__ kbf1,
        const bf16x8* __restrict__ W2F,
        const float* __restrict__ b2, const float* __restrict__ W3,
        const float* __restrict__ b3,
        float* __restrict__ z3ws) {
    const int tid  = threadIdx.x;
    const int lane = tid & 63, wv = tid >> 6;
    // bijective XCD swizzle: 6656 = 8*832 -> same-b jobs share an XCD L2
    const int bid  = (blockIdx.x & 7) * 832 + (blockIdx.x >> 3);
    const int job  = bid * 4 + wv;
    const int bn   = job / NTILE, mt = job % NTILE;
    const int b    = bn >> 4;
    const int cl   = lane & 15, rg = lane >> 4;

    __shared__ __align__(16) short X1[4][16][104];   // per-wave slice, no barrier

    // zero k-pad cols 80..95 (W2F pad rows are 0, but NaN*0 guard requires finite A)
    #pragma unroll
    for (int i = 0; i < 4; ++i)
        X1[wv][(lane >> 4) + 4 * i][80 + (lane & 15)] = 0;

    // layer-1 operands (single-use, coalesced, L2-hot)
    bf16x8 a0 = kbf0[(b * NTILE + mt) * 64 + lane];
    bf16x8 a1 = kbf1[(b * NTILE + mt) * 64 + lane];
    bf16x8 bfr[10];
    #pragma unroll
    for (int f = 0; f < 10; ++f) bfr[f] = Bnf[(size_t)bn * 640 + f * 64 + lane];
    float qwv[5];
    #pragma unroll
    for (int nt = 0; nt < 5; ++nt) qwv[nt] = QW[bn * J1 + cl + 16 * nt];

    // layer 1: Z1 = K @ Bn + QW
    f32x4 acc[5];
    #pragma unroll
    for (int nt = 0; nt < 5; ++nt) {
        float qv = qwv[nt];
        acc[nt][0] = qv; acc[nt][1] = qv; acc[nt][2] = qv; acc[nt][3] = qv;
    }
    #pragma unroll
    for (int nt = 0; nt < 5; ++nt) {
        acc[nt] = __builtin_amdgcn_mfma_f32_16x16x32_bf16(a0, bfr[nt * 2 + 0], acc[nt], 0, 0, 0);
        acc[nt] = __builtin_amdgcn_mfma_f32_16x16x32_bf16(a1, bfr[nt * 2 + 1], acc[nt], 0, 0, 0);
    }

    // sigmoid -> X1 (C layout: row = rg*4+i, col = cl+16nt)
    #pragma unroll
    for (int nt = 0; nt < 5; ++nt)
        #pragma unroll
        for (int i = 0; i < 4; ++i)
            X1[wv][rg * 4 + i][cl + 16 * nt] = f2b(sigmoidf_(acc[nt][i]));

    // layer-2 operands (loaded after layer 1 to bound register pressure)
    bf16x8 w2f[9];
    #pragma unroll
    for (int f = 0; f < 9; ++f) w2f[f] = W2F[f * 64 + lane];
    float b2v[3], w3v[3];
    #pragma unroll
    for (int nt = 0; nt < 3; ++nt) {
        int m  = cl + 16 * nt;
        int mc = m < J2 ? m : J2 - 1;
        b2v[nt] = b2[mc];
        w3v[nt] = (m < J2) ? W3[mc] : 0.0f;
    }
    const float b3v = b3[0];

    // layer 2: Z2 = X1 @ W2 + b2
    f32x4 acc2[3];
    #pragma unroll
    for (int nt = 0; nt < 3; ++nt) {
        float bv = b2v[nt];
        acc2[nt][0] = bv; acc2[nt][1] = bv; acc2[nt][2] = bv; acc2[nt][3] = bv;
    }
    #pragma unroll
    for (int ks = 0; ks < 3; ++ks) {
        bf16x8 a2 = *(const bf16x8*)&X1[wv][cl][8 * rg + 32 * ks];
        acc2[0] = __builtin_amdgcn_mfma_f32_16x16x32_bf16(a2, w2f[0 + ks], acc2[0], 0, 0, 0);
        acc2[1] = __builtin_amdgcn_mfma_f32_16x16x32_bf16(a2, w2f[3 + ks], acc2[1], 0, 0, 0);
        acc2[2] = __builtin_amdgcn_mfma_f32_16x16x32_bf16(a2, w2f[6 + ks], acc2[2], 0, 0, 0);
    }

    // layer 3 + 16-lane reduce
    float p0 = 0.f, p1 = 0.f, p2 = 0.f, p3 = 0.f;
    #pragma unroll
    for (int nt = 0; nt < 3; ++nt) {
        p0 = fmaf(sigmoidf_(acc2[nt][0]), w3v[nt], p0);
        p1 = fmaf(sigmoidf_(acc2[nt][1]), w3v[nt], p1);
        p2 = fmaf(sigmoidf_(acc2[nt][2]), w3v[nt], p2);
        p3 = fmaf(sigmoidf_(acc2[nt][3]), w3v[nt], p3);
    }
    #pragma unroll
    for (int off = 1; off < 16; off <<= 1) {
        p0 += __shfl_xor(p0, off);
        p1 += __shfl_xor(p1, off);
        p2 += __shfl_xor(p2, off);
        p3 += __shfl_xor(p3, off);
    }
    if (cl == 0) {
        float* zp = z3ws + (size_t)bn * ZSTR + mt * 16 + rg * 4;
        zp[0] = p0 + b3v; zp[1] = p1 + b3v; zp[2] = p2 + b3v; zp[3] = p3 + b3v;
    }
}

// ---- softmax + weighted sum: block per bn (verified round-5 code) -------
__global__ __launch_bounds__(256) void softmax_pv(
        const float* __restrict__ keys, const int* __restrict__ keys_length,
        const float* __restrict__ z3ws, float* __restrict__ out) {
    const int tid = threadIdx.x;
    const int bn  = (blockIdx.x & 7) * 256 + (blockIdx.x >> 3);  // XCD swizzle
    const int b   = bn >> 4;

    __shared__ float wsm[T_];
    __shared__ float part[256];
    __shared__ float red[8];

    const int L = keys_length[b];
    float s = (tid < T_) ? ((tid < L) ? z3ws[(size_t)bn * ZSTR + tid] : NEGV) * 0.125f
                         : -3.0e38f;

    float mx = s;
    #pragma unroll
    for (int off = 32; off > 0; off >>= 1) mx = fmaxf(mx, __shfl_xor(mx, off));
    if ((tid & 63) == 0) red[tid >> 6] = mx;
    __syncthreads();
    mx = fmaxf(fmaxf(red[0], red[1]), fmaxf(red[2], red[3]));

    float e = (tid < T_) ? __expf(s - mx) : 0.0f;
    float sm = e;
    #pragma unroll
    for (int off = 32; off > 0; off >>= 1) sm += __shfl_xor(sm, off);
    __syncthreads();
    if ((tid & 63) == 0) red[4 + (tid >> 6)] = sm;
    __syncthreads();
    sm = red[4] + red[5] + red[6] + red[7];

    if (tid < T_) wsm[tid] = e / sm;
    __syncthreads();

    const float* kb = keys + (size_t)b * T_ * H_;
    {
        int h = tid & 63, p = tid >> 6;
        float acc = 0.f;
        int tb = p * 50;
        #pragma unroll 5
        for (int t = tb; t < tb + 50; ++t)
            acc = fmaf(wsm[t], kb[(size_t)t * H_ + h], acc);
        part[tid] = acc;
    }
    __syncthreads();
    if (tid < 64) {
        out[bn * H_ + tid] = part[tid] + part[64 + tid] + part[128 + tid] + part[192 + tid];
    }
}

// --- fallback (no workspace): round-3 verified pure-VALU kernel ----------
__global__ __launch_bounds__(256, 3) void attn_nows(
        const float* __restrict__ queries, const float* __restrict__ keys,
        const int*   __restrict__ keys_length,
        const float* __restrict__ W1, const float* __restrict__ b1,
        const float* __restrict__ W2, const float* __restrict__ b2,
        const float* __restrict__ W3, const float* __restrict__ b3,
        float* __restrict__ out) {
    const int tid = threadIdx.x;
    const int bn = (blockIdx.x & 7) * 256 + (blockIdx.x >> 3);
    const int b  = bn >> 4;

    __shared__ float kT[H_][T_ + 1];
    __shared__ float wsm[T_];
    __shared__ float part[256];
    __shared__ float red[8];
    __shared__ float QWq[J1];

    for (int idx = tid; idx < T_ * H_; idx += 256) {
        int t = idx >> 6, h = idx & 63;
        kT[h][t] = keys[(b * T_ + t) * H_ + h];
    }
    if (tid < J1) {
        float acc = b1[tid];
        const float* qp = queries + bn * H_;
        for (int h = 0; h < H_; ++h)
            acc = fmaf(qp[h], W1[h * J1 + tid] + W1[(128 + h) * J1 + tid], acc);
        QWq[tid] = acc;
    }
    __syncthreads();

    const int tt = (tid < T_) ? tid : 0;
    const float* qp = queries + bn * H_;

    float qk[H_];
    #pragma unroll
    for (int h = 0; h < H_; ++h) qk[h] = qp[h] * kT[h][tt];

    float z2[J2];
    #pragma unroll
    for (int m = 0; m < J2; ++m) z2[m] = b2[m];

    #pragma unroll 1
    for (int c = 0; c < 4; ++c) {
        const int j0 = c * 20;
        float z1c[20];
        #pragma unroll
        for (int j = 0; j < 20; ++j) z1c[j] = QWq[j0 + j];
        #pragma unroll
        for (int h = 0; h < H_; ++h) {
            float kh = kT[h][tt];
            const float* Wd = W1 + (192 + h) * J1 + j0;
            const float* Wb = W1 + (64 + h) * J1 + j0;
            const float* Wc = W1 + (128 + h) * J1 + j0;
            #pragma unroll
            for (int j = 0; j < 20; ++j)
                z1c[j] = fmaf(qk[h], Wd[j], fmaf(kh, Wb[j] - Wc[j], z1c[j]));
        }
        #pragma unroll
        for (int j = 0; j < 20; ++j) {
            float x = sigmoidf_(z1c[j]);
            const float* w2 = W2 + (j0 + j) * J2;
            #pragma unroll
            for (int m = 0; m < J2; ++m) z2[m] = fmaf(x, w2[m], z2[m]);
        }
    }

    float z3 = b3[0];
    #pragma unroll
    for (int m = 0; m < J2; ++m) z3 = fmaf(sigmoidf_(z2[m]), W3[m], z3);

    const int L = keys_length[b];
    float s = (tid < T_) ? ((tid < L) ? z3 : NEGV) * 0.125f : -3.0e38f;

    float mx = s;
    #pragma unroll
    for (int off = 32; off > 0; off >>= 1) mx = fmaxf(mx, __shfl_xor(mx, off));
    if ((tid & 63) == 0) red[tid >> 6] = mx;
    __syncthreads();
    mx = fmaxf(fmaxf(red[0], red[1]), fmaxf(red[2], red[3]));

    float e = (tid < T_) ? __expf(s - mx) : 0.0f;
    float sm = e;
    #pragma unroll
    for (int off = 32; off > 0; off >>= 1) sm += __shfl_xor(sm, off);
    __syncthreads();
    if ((tid & 63) == 0) red[4 + (tid >> 6)] = sm;
    __syncthreads();
    sm = red[4] + red[5] + red[6] + red[7];

    if (tid < T_) wsm[tid] = e / sm;
    __syncthreads();

    {
        int h = tid & 63, p = tid >> 6;
        float acc = 0.f;
        int t0 = p * 50;
        for (int t = t0; t < t0 + 50; ++t)
            acc = fmaf(wsm[t], kT[h][t], acc);
        part[tid] = acc;
    }
    __syncthreads();
    if (tid < 64) {
        out[bn * H_ + tid] = part[tid] + part[64 + tid] + part[128 + tid] + part[192 + tid];
    }
}

extern "C" void kernel_launch(void* const* d_in, const int* in_sizes, int n_in,
                              void* d_out, int out_size, void* d_ws, size_t ws_size,
                              hipStream_t stream) {
    const float* queries = (const float*)d_in[0];
    const float* keys    = (const float*)d_in[1];
    const int*   klen    = (const int*)  d_in[2];
    const float* W1 = (const float*)d_in[3];
    const float* b1 = (const float*)d_in[4];
    const float* W2 = (const float*)d_in[5];
    const float* b2 = (const float*)d_in[6];
    const float* W3 = (const float*)d_in[7];
    const float* b3 = (const float*)d_in[8];
    float* out = (float*)d_out;

    // ws layout (16B-aligned segments):
    // QW  [2048*80 f32]            =   655,360 B
    // kbf0[128*13*64 x 16B]        = 1,703,936 B
    // kbf1[same]                   = 1,703,936 B
    // Bnf [2048*640 x 16B]         = 20,971,520 B
    // z3  [2048*208 f32]           = 1,703,936 B
    // W2F [2304 u32]               =     9,216 B
    const size_t nkbf = (size_t)B_ * NTILE * 64;
    const size_t need = 655360 + 2 * 1703936 + 20971520 + 1703936 + 9216;

    if (ws_size >= need) {
        float*  QW   = (float*)d_ws;
        bf16x8* kbf0 = (bf16x8*)((char*)d_ws + 655360);
        bf16x8* kbf1 = kbf0 + nkbf;
        bf16x8* Bnf  = kbf1 + nkbf;
        float*  z3ws = (float*)((char*)(Bnf) + 20971520);
        unsigned* W2F = (unsigned*)((char*)z3ws + 1703936);

        prep_all<<<dim3(QW_BLK + BNF_BLK + KBF_BLK + W2F_BLK), dim3(256), 0, stream>>>(
            queries, keys, W1, b1, W2, QW, Bnf, kbf0, kbf1, W2F);
        score_mfma<<<dim3(6656), dim3(256), 0, stream>>>(
            QW, Bnf, kbf0, kbf1, (const bf16x8*)W2F, b2, W3, b3, z3ws);
        softmax_pv<<<dim3(B_ * N_), dim3(256), 0, stream>>>(keys, klen, z3ws, out);
    } else {
        attn_nows<<<dim3(B_ * N_), dim3(256), 0, stream>>>(
            queries, keys, klen, W1, b1, W2, b2, W3, b3, out);
    }
}